// Round 19
// baseline (180.450 us; speedup 1.0000x reference)
//
#include <hip/hip_runtime.h>
#include <stdint.h>

// Problem constants (B=8, T=1024, D=512, H=8, dk=64)
#define Bc 8
#define Tc 1024
#define Dc 512
#define Hc 8

typedef __bf16 bf16x8 __attribute__((ext_vector_type(8)));
typedef float f32x4 __attribute__((ext_vector_type(4)));
typedef unsigned short ushort8v __attribute__((ext_vector_type(8)));

#define NEGBF 0xF14Au   // bf16(-1.0e30)

__device__ __forceinline__ unsigned short f2bf(float f) {
    union { float f; uint32_t u; } v; v.f = f;
    uint32_t u = v.u;
    u += 0x7fffu + ((u >> 16) & 1u);   // RNE
    return (unsigned short)(u >> 16);
}
__device__ __forceinline__ unsigned short f2bf_native(float f) {
    __bf16 b = (__bf16)f;
    return *(unsigned short*)&b;
}
__device__ __forceinline__ f32x4 mfma16(bf16x8 a, bf16x8 b, f32x4 c) {
    return __builtin_amdgcn_mfma_f32_16x16x32_bf16(a, b, c, 0, 0, 0);
}
// async global->LDS, 16B per lane, dest = wave-uniform base + lane*16
__device__ __forceinline__ void gl16(const unsigned short* g, unsigned short* l) {
    __builtin_amdgcn_global_load_lds(
        (const __attribute__((address_space(1))) uint32_t*)g,
        (__attribute__((address_space(3))) uint32_t*)l, 16, 0, 0);
}

// log2(e) folding: score_2dom = (ac+bd) * 0.125 * log2e
#define SC2 0.1803368801f

// ---------------------------------------------------------------------------
// prep: [0,32768) pack mask bits; [32768,33408) W f32->bf16 (5 matrices);
// [33408,39808) q/k/v/pos f32->bf16.
// ---------------------------------------------------------------------------
__global__ __launch_bounds__(256) void prep(
    const int* __restrict__ mask, uint32_t* __restrict__ bits,
    const float* __restrict__ Wq, const float* __restrict__ Wk,
    const float* __restrict__ Wv, const float* __restrict__ Wp,
    const float* __restrict__ Wo, unsigned short* __restrict__ Wb,
    const float* __restrict__ q, const float* __restrict__ k,
    const float* __restrict__ v, const float* __restrict__ p,
    unsigned short* __restrict__ qb, unsigned short* __restrict__ kb,
    unsigned short* __restrict__ vb, unsigned short* __restrict__ pb)
{
    int bid = blockIdx.x;
    if (bid < 32768) {
        int wid = (bid * 256 + threadIdx.x) >> 6;
        int lane = threadIdx.x & 63;
        unsigned long long bl = __ballot(mask[(size_t)wid * 64 + lane] != 0);
        if (lane == 0)  bits[wid * 2]     = (uint32_t)bl;
        if (lane == 32) bits[wid * 2 + 1] = (uint32_t)(bl >> 32);
    } else if (bid < 33408) {
        int i = (bid - 32768) * 2048 + threadIdx.x * 8;
        int m = i >> 18, r = i & 262143;
        const float* Ws[5] = {Wq, Wk, Wv, Wp, Wo};
        const float* s = Ws[m] + r;
        ushort8v o;
#pragma unroll
        for (int j = 0; j < 8; ++j) o[j] = f2bf(s[j]);
        *(ushort8v*)(Wb + i) = o;
    } else {
        size_t i = (size_t)(bid - 33408) * 2048 + threadIdx.x * 8;
        const float* src; unsigned short* dst; size_t off;
        if (i < 4194304)       { src = q; dst = qb; off = i; }
        else if (i < 8388608)  { src = k; dst = kb; off = i - 4194304; }
        else if (i < 12582912) { src = v; dst = vb; off = i - 8388608; }
        else                   { src = p; dst = pb; off = i - 12582912; }
        ushort8v o;
#pragma unroll
        for (int j = 0; j < 8; ++j) o[j] = f2bf(src[off + j]);
        *(ushort8v*)(dst + off) = o;
    }
}

// ---------------------------------------------------------------------------
// proj4 v4: z=0 Q->(qu,qv), z=1 K->kh (PRE-SCALED by SC2), z=2 V->vT,
// z=3 pos->ph.  64-row n-tiles (grid 1600 = 8*200 bijective) -> 48KB LDS,
// 3 blocks/CU; dbuf + XOR swizzle + counted-vmcnt raw-barrier pipeline.
// ---------------------------------------------------------------------------
__global__ __launch_bounds__(256) void proj4(
    const unsigned short* __restrict__ qb, const unsigned short* __restrict__ kb,
    const unsigned short* __restrict__ vb, const unsigned short* __restrict__ pb,
    const unsigned short* __restrict__ Wb,
    const float* __restrict__ bq, const float* __restrict__ bk,
    const float* __restrict__ bv,
    const float* __restrict__ bias_u, const float* __restrict__ bias_v,
    unsigned short* __restrict__ qu, unsigned short* __restrict__ qv,
    unsigned short* __restrict__ kh, unsigned short* __restrict__ vT,
    unsigned short* __restrict__ ph)
{
    int id = blockIdx.x;
    int wg = (id & 7) * 200 + (id >> 3);          // 1600 = 8*200 bijective
    int z, rem;
    if (wg < 512)       { z = 0; rem = wg; }
    else if (wg < 1024) { z = 1; rem = wg - 512; }
    else if (wg < 1536) { z = 2; rem = wg - 1024; }
    else                { z = 3; rem = wg - 1536; }
    const int m0 = (rem & 3) * 128, n0 = (rem >> 2) * 64;
    const unsigned short* A = z == 0 ? qb : z == 1 ? kb : z == 2 ? vb : pb;
    const unsigned short* W = Wb + (size_t)z * 262144;

    __shared__ unsigned short As[2][64][64];
    __shared__ unsigned short Bs[2][128][64];
    const int tid = threadIdx.x, lane = tid & 63, wave = tid >> 6;
    const int lrow = lane & 15, lkg = lane >> 4;
    const int wr = (wave >> 1) * 32, wc = (wave & 1) * 64;
    const int srow = lane >> 3;
    const int scol = ((lane & 7) ^ (srow & 7)) * 8;   // swizzled source col
    const int swr  = (lrow & 7) * 8;                  // read-side XOR

    f32x4 acc[2][4];
#pragma unroll
    for (int i = 0; i < 2; ++i)
#pragma unroll
        for (int j = 0; j < 4; ++j) acc[i][j] = f32x4{0.f, 0.f, 0.f, 0.f};

    // prologue: stage tile 0 (6 gl16/wave)
#pragma unroll
    for (int it = 0; it < 2; ++it) {
        int r8 = (wave * 2 + it) * 8;
        gl16(A + (size_t)(n0 + r8 + srow) * 512 + scol, &As[0][r8][0]);
    }
#pragma unroll
    for (int it = 0; it < 4; ++it) {
        int r8 = (wave * 4 + it) * 8;
        gl16(W + (size_t)(m0 + r8 + srow) * 512 + scol, &Bs[0][r8][0]);
    }

    int cur = 0;
    for (int kt = 0; kt < 512; kt += 64) {
        if (kt + 64 < 512) {   // prefetch next tile (6 gl16), keep in flight
#pragma unroll
            for (int it = 0; it < 2; ++it) {
                int r8 = (wave * 2 + it) * 8;
                gl16(A + (size_t)(n0 + r8 + srow) * 512 + kt + 64 + scol, &As[cur ^ 1][r8][0]);
            }
#pragma unroll
            for (int it = 0; it < 4; ++it) {
                int r8 = (wave * 4 + it) * 8;
                gl16(W + (size_t)(m0 + r8 + srow) * 512 + kt + 64 + scol, &Bs[cur ^ 1][r8][0]);
            }
            asm volatile("s_waitcnt vmcnt(6)" ::: "memory");   // tile-kt landed
        } else {
            asm volatile("s_waitcnt vmcnt(0)" ::: "memory");
        }
        __builtin_amdgcn_s_barrier();
#pragma unroll
        for (int kk = 0; kk < 2; ++kk) {
            bf16x8 a[2], bb[4];
#pragma unroll
            for (int i = 0; i < 2; ++i)
                a[i] = *(const bf16x8*)&As[cur][wr + i * 16 + lrow][(kk * 32 + lkg * 8) ^ swr];
#pragma unroll
            for (int j = 0; j < 4; ++j)
                bb[j] = *(const bf16x8*)&Bs[cur][wc + j * 16 + lrow][(kk * 32 + lkg * 8) ^ swr];
#pragma unroll
            for (int i = 0; i < 2; ++i)
#pragma unroll
                for (int j = 0; j < 4; ++j)
                    acc[i][j] = mfma16(a[i], bb[j], acc[i][j]);
        }
        asm volatile("s_waitcnt lgkmcnt(0)" ::: "memory");
        __builtin_amdgcn_s_barrier();
        cur ^= 1;
    }

#pragma unroll
    for (int i = 0; i < 2; ++i) {
        int nbase = n0 + wr + i * 16 + lkg * 4;
#pragma unroll
        for (int j = 0; j < 4; ++j) {
            int m = m0 + wc + j * 16 + lrow;
            float bb = z == 0 ? bq[m] : z == 1 ? bk[m] : z == 2 ? bv[m] : 0.f;
            float bu = 0.f, bvv = 0.f;
            if (z == 0) { bu = bias_u[m]; bvv = bias_v[m]; }
#pragma unroll
            for (int qq = 0; qq < 4; ++qq) {
                int n = nbase + qq;
                float c = acc[i][j][qq] + bb;
                if (z == 0) {
                    qu[(size_t)n * 512 + m] = f2bf(c + bu);
                    qv[(size_t)n * 512 + m] = f2bf(c + bvv);
                } else if (z == 1) {
                    kh[(size_t)n * 512 + m] = f2bf(c * SC2);   // fold score scale into K
                } else if (z == 2) {
                    int b = n >> 10, t = n & 1023, h = m >> 6, d = m & 63;
                    vT[(((size_t)((b * 8 + h) * 64 + d)) << 10) + t] = f2bf(c);
                } else {
                    ph[(size_t)n * 512 + m] = f2bf(c);
                }
            }
        }
    }
}

// ---------------------------------------------------------------------------
// gemm_out v4: out[n,m] = x·Wo + bo (fp32 out).  64-row tiles, 512 blocks,
// dbuf + XOR swizzle + counted-vmcnt raw-barrier pipeline (6 loads/wave/tile).
// ---------------------------------------------------------------------------
__global__ __launch_bounds__(256) void gemm_out(
    const unsigned short* __restrict__ X, const unsigned short* __restrict__ Wob,
    const float* __restrict__ bo, float* __restrict__ fout)
{
    int id = blockIdx.x;
    int wg = (id & 7) * 64 + (id >> 3);           // 512 = 8*64 bijective
    const int m0 = (wg & 3) * 128, n0 = (wg >> 2) * 64;
    __shared__ unsigned short As[2][64][64];
    __shared__ unsigned short Bs[2][128][64];
    const int tid = threadIdx.x, lane = tid & 63, wave = tid >> 6;
    const int lrow = lane & 15, lkg = lane >> 4;
    const int wr = (wave >> 1) * 32, wc = (wave & 1) * 64;
    const int srow = lane >> 3;
    const int scol = ((lane & 7) ^ (srow & 7)) * 8;
    const int swr  = (lrow & 7) * 8;

    f32x4 acc[2][4];
#pragma unroll
    for (int i = 0; i < 2; ++i)
#pragma unroll
        for (int j = 0; j < 4; ++j) acc[i][j] = f32x4{0.f, 0.f, 0.f, 0.f};

#pragma unroll
    for (int it = 0; it < 2; ++it) {
        int r8 = (wave * 2 + it) * 8;
        gl16(X + (size_t)(n0 + r8 + srow) * 512 + scol, &As[0][r8][0]);
    }
#pragma unroll
    for (int it = 0; it < 4; ++it) {
        int r8 = (wave * 4 + it) * 8;
        gl16(Wob + (size_t)(m0 + r8 + srow) * 512 + scol, &Bs[0][r8][0]);
    }

    int cur = 0;
    for (int kt = 0; kt < 512; kt += 64) {
        if (kt + 64 < 512) {
#pragma unroll
            for (int it = 0; it < 2; ++it) {
                int r8 = (wave * 2 + it) * 8;
                gl16(X + (size_t)(n0 + r8 + srow) * 512 + kt + 64 + scol, &As[cur ^ 1][r8][0]);
            }
#pragma unroll
            for (int it = 0; it < 4; ++it) {
                int r8 = (wave * 4 + it) * 8;
                gl16(Wob + (size_t)(m0 + r8 + srow) * 512 + kt + 64 + scol, &Bs[cur ^ 1][r8][0]);
            }
            asm volatile("s_waitcnt vmcnt(6)" ::: "memory");
        } else {
            asm volatile("s_waitcnt vmcnt(0)" ::: "memory");
        }
        __builtin_amdgcn_s_barrier();
#pragma unroll
        for (int kk = 0; kk < 2; ++kk) {
            bf16x8 a[2], bb[4];
#pragma unroll
            for (int i = 0; i < 2; ++i)
                a[i] = *(const bf16x8*)&As[cur][wr + i * 16 + lrow][(kk * 32 + lkg * 8) ^ swr];
#pragma unroll
            for (int j = 0; j < 4; ++j)
                bb[j] = *(const bf16x8*)&Bs[cur][wc + j * 16 + lrow][(kk * 32 + lkg * 8) ^ swr];
#pragma unroll
            for (int i = 0; i < 2; ++i)
#pragma unroll
                for (int j = 0; j < 4; ++j)
                    acc[i][j] = mfma16(a[i], bb[j], acc[i][j]);
        }
        asm volatile("s_waitcnt lgkmcnt(0)" ::: "memory");
        __builtin_amdgcn_s_barrier();
        cur ^= 1;
    }
#pragma unroll
    for (int i = 0; i < 2; ++i) {
        int nbase = n0 + wr + i * 16 + lkg * 4;
#pragma unroll
        for (int j = 0; j < 4; ++j) {
            int m = m0 + wc + j * 16 + lrow;
            float bb = bo[m];
#pragma unroll
            for (int qq = 0; qq < 4; ++qq)
                fout[(size_t)(nbase + qq) * 512 + m] = acc[i][j][qq] + bb;
        }
    }
}

// ---------------------------------------------------------------------------
// attn13: FUSED bd_gemm + flash attention.
// Phase A: compute this block's shifted+masked BD strip (raw qv rows
//   u0..u0+64 x all p, via MFMA over 8 p-chunks staged in 8KB LDS) and
//   scatter through the linear-F map (F = 1025*u + p - 1023) into the slab,
//   keeping only F in [u0<<10, (u0+64)<<10).  The window test subsumes all
//   branch/edge cases (u==u0 branch2, extra-row u0+64, u_e==1024 garbage).
// Phase B: attn12's flash loop (dbuf K/V gl16, counted vmcnt(4), static-max
//   exp2, XOR swizzle) reading the L2/L3-hot slab rows back.
// ---------------------------------------------------------------------------
__global__ __launch_bounds__(256, 4) void attn13(
    const unsigned short* __restrict__ qu, const unsigned short* __restrict__ qv,
    const unsigned short* __restrict__ kh, const unsigned short* __restrict__ vT,
    const unsigned short* __restrict__ ph, const uint32_t* __restrict__ mbits,
    unsigned short* __restrict__ bds, unsigned short* __restrict__ xout,
    int b_base)
{
    int id = blockIdx.x, nid, b, rem;
    if (gridDim.x == 1024) {
        nid = (id & 7) * 128 + (id >> 3);
        b = b_base + (nid >> 7); rem = nid & 127;
    } else {
        nid = (id & 7) * 16 + (id >> 3);
        b = b_base; rem = nid;
    }
    const int h = rem >> 4, ublk = rem & 15;
    const int u0 = ublk * 64;

    __shared__ unsigned short sh[20480];   // 40,960 B total
    // phase A: Bp = sh[0..8192)  ([128][64] ph chunk)
    // phase B: Ks[cur] = sh[cur*4096 .. +4096), Vs[cur] = sh[8192 + cur*4096),
    //          Ps[wave] = sh[16384 + wave*1024)
    const int tid = threadIdx.x, lane = tid & 63, wave = tid >> 6;
    const int lrow = lane & 15, lkg = lane >> 4;
    const int srow = lane >> 3;
    const int scol = ((lane & 7) ^ (srow & 7)) * 8;   // swizzled source col
    const int swr  = (lrow & 7) * 8;                  // read-side XOR
    const f32x4 zero = {0.f, 0.f, 0.f, 0.f};

    const int zoff = (b - b_base) * 8 + h;
    unsigned short* slab = bds + ((size_t)zoff << 20);
    const uint32_t* mb = mbits + ((size_t)b << 15);
    const int Fmin = u0 << 10, Fmax = Fmin + 65536;

    // Q fragments for phase B (own rows only -> xout=qu aliasing is safe)
    const unsigned short* qub = qu + ((size_t)(b * 1024 + u0 + wave * 16 + lrow)) * 512 + h * 64;
    bf16x8 au0 = *(const bf16x8*)(qub + lkg * 8);
    bf16x8 au1 = *(const bf16x8*)(qub + 32 + lkg * 8);

    // ---------------- Phase A: BD strip ----------------
    {
        const unsigned short* qvb = qv + ((size_t)(b * 1024 + u0 + wave * 16 + lrow)) * 512 + h * 64;
        bf16x8 a0 = *(const bf16x8*)(qvb + lkg * 8);
        bf16x8 a1 = *(const bf16x8*)(qvb + 32 + lkg * 8);
        // extra raw row u0+64 (broadcast to all lanes); for ublk=15 this reads
        // the next batch's row 0 (valid memory) and is fully excluded by Fmax.
        const unsigned short* qve = qv + ((size_t)(b * 1024 + u0 + 64)) * 512 + h * 64;
        bf16x8 ae0 = *(const bf16x8*)(qve + lkg * 8);
        bf16x8 ae1 = *(const bf16x8*)(qve + 32 + lkg * 8);

        const int u_w = u0 + wave * 16 + lkg * 4;      // +qq
        const int u_e = u0 + 64;

        for (int c = 0; c < 8; ++c) {
            // stage ph chunk c: rows c*128..+128, 4 gl16/wave
#pragma unroll
            for (int it = 0; it < 4; ++it) {
                int r8 = wave * 32 + it * 8;
                gl16(ph + ((size_t)(c * 128 + r8 + srow)) * 512 + h * 64 + scol, &sh[r8 * 64]);
            }
            __syncthreads();

            f32x4 accA[8], accE[2];
#pragma unroll
            for (int pt = 0; pt < 8; ++pt) accA[pt] = zero;
            accE[0] = zero; accE[1] = zero;
#pragma unroll
            for (int kk = 0; kk < 2; ++kk) {
                bf16x8 av = kk ? a1 : a0;
                bf16x8 ev = kk ? ae1 : ae0;
#pragma unroll
                for (int pt = 0; pt < 8; ++pt) {
                    bf16x8 bb = *(const bf16x8*)&sh[(pt * 16 + lrow) * 64 + ((kk * 32 + lkg * 8) ^ swr)];
                    accA[pt] = mfma16(av, bb, accA[pt]);
                }
#pragma unroll
                for (int t = 0; t < 2; ++t) {
                    int pt2 = wave * 2 + t;
                    bf16x8 bb = *(const bf16x8*)&sh[(pt2 * 16 + lrow) * 64 + ((kk * 32 + lkg * 8) ^ swr)];
                    accE[t] = mfma16(ev, bb, accE[t]);
                }
            }

            // scatter main rows: F = 1025*u + p - 1023, p = c*128 + pt*16 + lrow
#pragma unroll
            for (int qq = 0; qq < 4; ++qq) {
                int u = u_w + qq;
                int Fb0 = 1025 * u + c * 128 + lrow - 1023;
                int w0 = Fb0 >> 5, sh5 = Fb0 & 31;
                uint32_t w0v = mb[w0], w1v = mb[w0 + 1], w2v = mb[w0 + 2],
                         w3v = mb[w0 + 3], w4v = mb[w0 + 4];
                uint64_t mm0 = ((uint64_t)w1v << 32) | w0v;
                uint64_t mm1 = ((uint64_t)w2v << 32) | w1v;
                uint64_t mm2 = ((uint64_t)w3v << 32) | w2v;
                uint64_t mm3 = ((uint64_t)w4v << 32) | w3v;
#pragma unroll
                for (int pt = 0; pt < 8; ++pt) {
                    uint64_t mm = (pt < 2) ? mm0 : (pt < 4) ? mm1 : (pt < 6) ? mm2 : mm3;
                    uint32_t bit = (uint32_t)(mm >> (sh5 + (pt & 1) * 16)) & 1u;
                    unsigned short val = bit ? f2bf_native(accA[pt][qq] * SC2)
                                             : (unsigned short)NEGBF;
                    int F = Fb0 + pt * 16;
                    if (F >= Fmin && F < Fmax) slab[F] = val;
                }
            }
            // scatter extra row (lanes lkg==0 carry cols lrow; rows identical -> [0])
            if (lkg == 0) {
#pragma unroll
                for (int t = 0; t < 2; ++t) {
                    int pt2 = wave * 2 + t;
                    int F = 1025 * u_e + c * 128 + pt2 * 16 + lrow - 1023;
                    uint32_t bit = (mb[F >> 5] >> (F & 31)) & 1u;
                    unsigned short val = bit ? f2bf_native(accE[t][0] * SC2)
                                             : (unsigned short)NEGBF;
                    if (F >= Fmin && F < Fmax) slab[F] = val;
                }
            }
            __syncthreads();
        }
        // diagonal t'=u'+1 (never produced by the linear map)
        if (tid < 64) {
            int du = u0 + tid;
            if (du < 1023) {
                const uint8_t* mrowbytes = (const uint8_t*)mbits + ((size_t)b << 17);
                uint32_t bit = (mrowbytes[du * 128 + ((du + 1) >> 3)] >> ((du + 1) & 7)) & 1;
                slab[((size_t)du << 10) + (du + 1)] = bit ? 0 : (unsigned short)NEGBF;
            }
        }
        asm volatile("s_waitcnt vmcnt(0)" ::: "memory");   // strip visible in L2
        __builtin_amdgcn_s_barrier();
    }

    // ---------------- Phase B: flash loop (attn12 structure) ----------------
    const int urow = u0 + wave * 16 + lkg * 4;           // +q
    const unsigned short* bdp[4];
#pragma unroll
    for (int q = 0; q < 4; ++q)
        bdp[q] = bds + ((size_t)zoff << 20) + (((size_t)(urow + q)) << 10) + lrow;
    const unsigned short* kbase = kh + ((size_t)(b * 1024)) * 512 + h * 64;
    const unsigned short* vbase = vT + (((size_t)((b * 8 + h) * 64)) << 10);

    f32x4 acc[4] = {zero, zero, zero, zero};
    float lsum[4] = {0.f, 0.f, 0.f, 0.f};

    // prologue: stage tile 0
#pragma unroll
    for (int it = 0; it < 2; ++it) {
        int r8 = (wave * 2 + it) * 8;
        gl16(kbase + (size_t)(r8 + srow) * 512 + scol, &sh[r8 * 64]);                 // Ks[0]
        gl16(vbase + ((size_t)(r8 + srow) << 10) + scol, &sh[8192 + r8 * 64]);        // Vs[0]
    }

    int cur = 0;
    for (int t0 = 0; t0 < 1024; t0 += 64) {
        f32x4 bdC[4];
#pragma unroll
        for (int j = 0; j < 4; ++j)
#pragma unroll
            for (int q = 0; q < 4; ++q)
                bdC[j][q] = __uint_as_float(((uint32_t)bdp[q][j * 16]) << 16);
#pragma unroll
        for (int q = 0; q < 4; ++q) bdp[q] += 64;

        if (t0 < 960) {   // prefetch next K/V tile into other buffer
#pragma unroll
            for (int it = 0; it < 2; ++it) {
                int r8 = (wave * 2 + it) * 8;
                gl16(kbase + (size_t)(t0 + 64 + r8 + srow) * 512 + scol,
                     &sh[(cur ^ 1) * 4096 + r8 * 64]);
                gl16(vbase + ((size_t)(r8 + srow) << 10) + t0 + 64 + scol,
                     &sh[8192 + (cur ^ 1) * 4096 + r8 * 64]);
            }
            asm volatile("s_waitcnt vmcnt(4)" ::: "memory");
        } else {
            asm volatile("s_waitcnt vmcnt(0)" ::: "memory");
        }
        __builtin_amdgcn_s_barrier();

        f32x4 s[4];
#pragma unroll
        for (int j = 0; j < 4; ++j) {
            bf16x8 k0 = *(const bf16x8*)&sh[cur * 4096 + (j * 16 + lrow) * 64 + ((lkg * 8) ^ swr)];
            bf16x8 k1 = *(const bf16x8*)&sh[cur * 4096 + (j * 16 + lrow) * 64 + ((32 + lkg * 8) ^ swr)];
            s[j] = mfma16(au1, k1, mfma16(au0, k0, bdC[j]));
        }
#pragma unroll
        for (int j = 0; j < 4; ++j) {
#pragma unroll
            for (int q = 0; q < 4; ++q) {
                float p = exp2f(s[j][q]);
                lsum[q] += p;
                int prow = lkg * 4 + q;
                sh[16384 + wave * 1024 + prow * 64 + ((j * 16 + lrow) ^ ((prow & 7) * 8))] = f2bf_native(p);
            }
        }
        bf16x8 pa0 = *(const bf16x8*)&sh[16384 + wave * 1024 + lrow * 64 + ((lkg * 8) ^ swr)];
        bf16x8 pa1 = *(const bf16x8*)&sh[16384 + wave * 1024 + lrow * 64 + ((32 + lkg * 8) ^ swr)];
#pragma unroll
        for (int jj = 0; jj < 4; ++jj) {
            bf16x8 vb0 = *(const bf16x8*)&sh[8192 + cur * 4096 + (jj * 16 + lrow) * 64 + ((lkg * 8) ^ swr)];
            bf16x8 vb1 = *(const bf16x8*)&sh[8192 + cur * 4096 + (jj * 16 + lrow) * 64 + ((32 + lkg * 8) ^ swr)];
            acc[jj] = mfma16(pa1, vb1, mfma16(pa0, vb0, acc[jj]));
        }
        asm volatile("s_waitcnt lgkmcnt(0)" ::: "memory");
        __builtin_amdgcn_s_barrier();
        cur ^= 1;
    }

#pragma unroll
    for (int off = 1; off < 16; off <<= 1)
#pragma unroll
        for (int q = 0; q < 4; ++q) lsum[q] += __shfl_xor(lsum[q], off);
#pragma unroll
    for (int q = 0; q < 4; ++q) {
        float inv = 1.0f / lsum[q];
        int u = urow + q;
#pragma unroll
        for (int jj = 0; jj < 4; ++jj) {
            int d = jj * 16 + lrow;
            xout[((size_t)(b * 1024 + u)) * 512 + h * 64 + d] = f2bf_native(acc[jj][q] * inv);
        }
    }
}

// ---------------------------------------------------------------------------
extern "C" void kernel_launch(void* const* d_in, const int* in_sizes, int n_in,
                              void* d_out, int out_size, void* d_ws, size_t ws_size,
                              hipStream_t stream) {
    const float* q    = (const float*)d_in[0];
    const float* k    = (const float*)d_in[1];
    const float* v    = (const float*)d_in[2];
    const float* pos  = (const float*)d_in[3];
    const int*   mask = (const int*)d_in[4];
    const float* Wq   = (const float*)d_in[5];
    const float* bq   = (const float*)d_in[6];
    const float* Wk   = (const float*)d_in[7];
    const float* bk   = (const float*)d_in[8];
    const float* Wv   = (const float*)d_in[9];
    const float* bv   = (const float*)d_in[10];
    const float* Wo   = (const float*)d_in[11];
    const float* bo   = (const float*)d_in[12];
    const float* Wp   = (const float*)d_in[13];
    const float* bias_u = (const float*)d_in[14];
    const float* bias_v = (const float*)d_in[15];
    float* out = (float*)d_out;

    unsigned short* ws = (unsigned short*)d_ws;
    constexpr size_t NQ  = (size_t)Bc * Tc * Dc;          // 4,194,304 elems
    constexpr size_t NP  = (size_t)Tc * Dc;               // 524,288
    constexpr size_t NMB = (size_t)Bc * Tc * 32;          // 262,144 words
    constexpr size_t NWB = (size_t)5 * 262144;            // 1,310,720 elems
    unsigned short* ws_qu = ws;
    unsigned short* ws_qv = ws_qu + NQ;
    unsigned short* ws_kh = ws_qv + NQ;
    unsigned short* ws_vT = ws_kh + NQ;
    unsigned short* ws_ph = ws_vT + NQ;
    uint32_t*       ws_mb = (uint32_t*)(ws_ph + NP);
    unsigned short* ws_wb = (unsigned short*)(ws_mb + NMB);
    unsigned short* ws_qb = ws_wb + NWB;      // conversion area (dead after proj4)
    unsigned short* ws_kb = ws_qb + NQ;
    unsigned short* ws_vb = ws_kb + NQ;
    unsigned short* ws_pb = ws_vb + NQ;
    unsigned short* ws_bd = ws_qb;            // BD overlays the conversion area

    constexpr size_t BD_FULL  = (size_t)64 * 1024 * 1024;   // elems
    const size_t base_bytes = (4 * NQ + NP + NWB) * 2 + NMB * 4;
    const bool full  = ws_size >= base_bytes + BD_FULL * 2;

    dim3 blk(256);
    prep<<<39808, blk, 0, stream>>>(mask, ws_mb, Wq, Wk, Wv, Wp, Wo, ws_wb,
                                    q, k, v, pos, ws_qb, ws_kb, ws_vb, ws_pb);
    proj4<<<1600, blk, 0, stream>>>(ws_qb, ws_kb, ws_vb, ws_pb, ws_wb, bq, bk, bv,
                                    bias_u, bias_v, ws_qu, ws_qv, ws_kh, ws_vT, ws_ph);

    // attn13 output overlays ws_qu (each block reads only its own qu rows
    // before writing the same rows; qv stays intact for phase A).
    if (full) {
        attn13<<<1024, blk, 0, stream>>>(ws_qu, ws_qv, ws_kh, ws_vT, ws_ph,
                                         ws_mb, ws_bd, ws_qu, 0);
        gemm_out<<<512, blk, 0, stream>>>(ws_qu, ws_wb + 4 * 262144, bo, out);
    } else {
        for (int b = 0; b < 8; ++b)
            attn13<<<128, blk, 0, stream>>>(ws_qu, ws_qv, ws_kh, ws_vT, ws_ph,
                                            ws_mb, ws_bd, ws_qu, b);
        gemm_out<<<512, blk, 0, stream>>>(ws_qu, ws_wb + 4 * 262144, bo, out);
    }
}

// Round 20
// 173.150 us; speedup vs baseline: 1.0422x; 1.0422x over previous
//
#include <hip/hip_runtime.h>
#include <stdint.h>

// Problem constants (B=8, T=1024, D=512, H=8, dk=64)
#define Bc 8
#define Tc 1024
#define Dc 512
#define Hc 8

typedef __bf16 bf16x8 __attribute__((ext_vector_type(8)));
typedef float f32x4 __attribute__((ext_vector_type(4)));
typedef unsigned short ushort8v __attribute__((ext_vector_type(8)));

#define NEGBF 0xF14Au   // bf16(-1.0e30)

__device__ __forceinline__ unsigned short f2bf(float f) {
    union { float f; uint32_t u; } v; v.f = f;
    uint32_t u = v.u;
    u += 0x7fffu + ((u >> 16) & 1u);   // RNE
    return (unsigned short)(u >> 16);
}
__device__ __forceinline__ unsigned short f2bf_native(float f) {
    __bf16 b = (__bf16)f;
    return *(unsigned short*)&b;
}
__device__ __forceinline__ f32x4 mfma16(bf16x8 a, bf16x8 b, f32x4 c) {
    return __builtin_amdgcn_mfma_f32_16x16x32_bf16(a, b, c, 0, 0, 0);
}
// async global->LDS, 16B per lane, dest = wave-uniform base + lane*16
__device__ __forceinline__ void gl16(const unsigned short* g, unsigned short* l) {
    __builtin_amdgcn_global_load_lds(
        (const __attribute__((address_space(1))) uint32_t*)g,
        (__attribute__((address_space(3))) uint32_t*)l, 16, 0, 0);
}

// log2(e) folding: score_2dom = (ac+bd) * 0.125 * log2e
#define SC2 0.1803368801f

// ---------------------------------------------------------------------------
// prep: [0,32768) pack mask bits; [32768,33408) W f32->bf16 (5 matrices);
// [33408,39808) q/k/v/pos f32->bf16.
// ---------------------------------------------------------------------------
__global__ __launch_bounds__(256) void prep(
    const int* __restrict__ mask, uint32_t* __restrict__ bits,
    const float* __restrict__ Wq, const float* __restrict__ Wk,
    const float* __restrict__ Wv, const float* __restrict__ Wp,
    const float* __restrict__ Wo, unsigned short* __restrict__ Wb,
    const float* __restrict__ q, const float* __restrict__ k,
    const float* __restrict__ v, const float* __restrict__ p,
    unsigned short* __restrict__ qb, unsigned short* __restrict__ kb,
    unsigned short* __restrict__ vb, unsigned short* __restrict__ pb)
{
    int bid = blockIdx.x;
    if (bid < 32768) {
        int wid = (bid * 256 + threadIdx.x) >> 6;
        int lane = threadIdx.x & 63;
        unsigned long long bl = __ballot(mask[(size_t)wid * 64 + lane] != 0);
        if (lane == 0)  bits[wid * 2]     = (uint32_t)bl;
        if (lane == 32) bits[wid * 2 + 1] = (uint32_t)(bl >> 32);
    } else if (bid < 33408) {
        int i = (bid - 32768) * 2048 + threadIdx.x * 8;
        int m = i >> 18, r = i & 262143;
        const float* Ws[5] = {Wq, Wk, Wv, Wp, Wo};
        const float* s = Ws[m] + r;
        ushort8v o;
#pragma unroll
        for (int j = 0; j < 8; ++j) o[j] = f2bf(s[j]);
        *(ushort8v*)(Wb + i) = o;
    } else {
        size_t i = (size_t)(bid - 33408) * 2048 + threadIdx.x * 8;
        const float* src; unsigned short* dst; size_t off;
        if (i < 4194304)       { src = q; dst = qb; off = i; }
        else if (i < 8388608)  { src = k; dst = kb; off = i - 4194304; }
        else if (i < 12582912) { src = v; dst = vb; off = i - 8388608; }
        else                   { src = p; dst = pb; off = i - 12582912; }
        ushort8v o;
#pragma unroll
        for (int j = 0; j < 8; ++j) o[j] = f2bf(src[off + j]);
        *(ushort8v*)(dst + off) = o;
    }
}

// ---------------------------------------------------------------------------
// proj4 v4: z=0 Q->(qu,qv), z=1 K->kh (PRE-SCALED by SC2), z=2 V->vT,
// z=3 pos->ph.  64-row n-tiles (grid 1600 = 8*200 bijective) -> 48KB LDS,
// 3 blocks/CU; dbuf + XOR swizzle + counted-vmcnt raw-barrier pipeline.
// ---------------------------------------------------------------------------
__global__ __launch_bounds__(256) void proj4(
    const unsigned short* __restrict__ qb, const unsigned short* __restrict__ kb,
    const unsigned short* __restrict__ vb, const unsigned short* __restrict__ pb,
    const unsigned short* __restrict__ Wb,
    const float* __restrict__ bq, const float* __restrict__ bk,
    const float* __restrict__ bv,
    const float* __restrict__ bias_u, const float* __restrict__ bias_v,
    unsigned short* __restrict__ qu, unsigned short* __restrict__ qv,
    unsigned short* __restrict__ kh, unsigned short* __restrict__ vT,
    unsigned short* __restrict__ ph)
{
    int id = blockIdx.x;
    int wg = (id & 7) * 200 + (id >> 3);          // 1600 = 8*200 bijective
    int z, rem;
    if (wg < 512)       { z = 0; rem = wg; }
    else if (wg < 1024) { z = 1; rem = wg - 512; }
    else if (wg < 1536) { z = 2; rem = wg - 1024; }
    else                { z = 3; rem = wg - 1536; }
    const int m0 = (rem & 3) * 128, n0 = (rem >> 2) * 64;
    const unsigned short* A = z == 0 ? qb : z == 1 ? kb : z == 2 ? vb : pb;
    const unsigned short* W = Wb + (size_t)z * 262144;

    __shared__ unsigned short As[2][64][64];
    __shared__ unsigned short Bs[2][128][64];
    const int tid = threadIdx.x, lane = tid & 63, wave = tid >> 6;
    const int lrow = lane & 15, lkg = lane >> 4;
    const int wr = (wave >> 1) * 32, wc = (wave & 1) * 64;
    const int srow = lane >> 3;
    const int scol = ((lane & 7) ^ (srow & 7)) * 8;   // swizzled source col
    const int swr  = (lrow & 7) * 8;                  // read-side XOR

    f32x4 acc[2][4];
#pragma unroll
    for (int i = 0; i < 2; ++i)
#pragma unroll
        for (int j = 0; j < 4; ++j) acc[i][j] = f32x4{0.f, 0.f, 0.f, 0.f};

    // prologue: stage tile 0 (6 gl16/wave)
#pragma unroll
    for (int it = 0; it < 2; ++it) {
        int r8 = (wave * 2 + it) * 8;
        gl16(A + (size_t)(n0 + r8 + srow) * 512 + scol, &As[0][r8][0]);
    }
#pragma unroll
    for (int it = 0; it < 4; ++it) {
        int r8 = (wave * 4 + it) * 8;
        gl16(W + (size_t)(m0 + r8 + srow) * 512 + scol, &Bs[0][r8][0]);
    }

    int cur = 0;
    for (int kt = 0; kt < 512; kt += 64) {
        if (kt + 64 < 512) {   // prefetch next tile (6 gl16), keep in flight
#pragma unroll
            for (int it = 0; it < 2; ++it) {
                int r8 = (wave * 2 + it) * 8;
                gl16(A + (size_t)(n0 + r8 + srow) * 512 + kt + 64 + scol, &As[cur ^ 1][r8][0]);
            }
#pragma unroll
            for (int it = 0; it < 4; ++it) {
                int r8 = (wave * 4 + it) * 8;
                gl16(W + (size_t)(m0 + r8 + srow) * 512 + kt + 64 + scol, &Bs[cur ^ 1][r8][0]);
            }
            asm volatile("s_waitcnt vmcnt(6)" ::: "memory");   // tile-kt landed
        } else {
            asm volatile("s_waitcnt vmcnt(0)" ::: "memory");
        }
        __builtin_amdgcn_s_barrier();
#pragma unroll
        for (int kk = 0; kk < 2; ++kk) {
            bf16x8 a[2], bb[4];
#pragma unroll
            for (int i = 0; i < 2; ++i)
                a[i] = *(const bf16x8*)&As[cur][wr + i * 16 + lrow][(kk * 32 + lkg * 8) ^ swr];
#pragma unroll
            for (int j = 0; j < 4; ++j)
                bb[j] = *(const bf16x8*)&Bs[cur][wc + j * 16 + lrow][(kk * 32 + lkg * 8) ^ swr];
#pragma unroll
            for (int i = 0; i < 2; ++i)
#pragma unroll
                for (int j = 0; j < 4; ++j)
                    acc[i][j] = mfma16(a[i], bb[j], acc[i][j]);
        }
        asm volatile("s_waitcnt lgkmcnt(0)" ::: "memory");
        __builtin_amdgcn_s_barrier();
        cur ^= 1;
    }

#pragma unroll
    for (int i = 0; i < 2; ++i) {
        int nbase = n0 + wr + i * 16 + lkg * 4;
#pragma unroll
        for (int j = 0; j < 4; ++j) {
            int m = m0 + wc + j * 16 + lrow;
            float bb = z == 0 ? bq[m] : z == 1 ? bk[m] : z == 2 ? bv[m] : 0.f;
            float bu = 0.f, bvv = 0.f;
            if (z == 0) { bu = bias_u[m]; bvv = bias_v[m]; }
#pragma unroll
            for (int qq = 0; qq < 4; ++qq) {
                int n = nbase + qq;
                float c = acc[i][j][qq] + bb;
                if (z == 0) {
                    qu[(size_t)n * 512 + m] = f2bf(c + bu);
                    qv[(size_t)n * 512 + m] = f2bf(c + bvv);
                } else if (z == 1) {
                    kh[(size_t)n * 512 + m] = f2bf(c * SC2);   // fold score scale into K
                } else if (z == 2) {
                    int b = n >> 10, t = n & 1023, h = m >> 6, d = m & 63;
                    vT[(((size_t)((b * 8 + h) * 64 + d)) << 10) + t] = f2bf(c);
                } else {
                    ph[(size_t)n * 512 + m] = f2bf(c);
                }
            }
        }
    }
}

// ---------------------------------------------------------------------------
// gemm_out v4: out[n,m] = x·Wo + bo (fp32 out).  64-row tiles, 512 blocks,
// dbuf + XOR swizzle + counted-vmcnt raw-barrier pipeline (6 loads/wave/tile).
// ---------------------------------------------------------------------------
__global__ __launch_bounds__(256) void gemm_out(
    const unsigned short* __restrict__ X, const unsigned short* __restrict__ Wob,
    const float* __restrict__ bo, float* __restrict__ fout)
{
    int id = blockIdx.x;
    int wg = (id & 7) * 64 + (id >> 3);           // 512 = 8*64 bijective
    const int m0 = (wg & 3) * 128, n0 = (wg >> 2) * 64;
    __shared__ unsigned short As[2][64][64];
    __shared__ unsigned short Bs[2][128][64];
    const int tid = threadIdx.x, lane = tid & 63, wave = tid >> 6;
    const int lrow = lane & 15, lkg = lane >> 4;
    const int wr = (wave >> 1) * 32, wc = (wave & 1) * 64;
    const int srow = lane >> 3;
    const int scol = ((lane & 7) ^ (srow & 7)) * 8;
    const int swr  = (lrow & 7) * 8;

    f32x4 acc[2][4];
#pragma unroll
    for (int i = 0; i < 2; ++i)
#pragma unroll
        for (int j = 0; j < 4; ++j) acc[i][j] = f32x4{0.f, 0.f, 0.f, 0.f};

#pragma unroll
    for (int it = 0; it < 2; ++it) {
        int r8 = (wave * 2 + it) * 8;
        gl16(X + (size_t)(n0 + r8 + srow) * 512 + scol, &As[0][r8][0]);
    }
#pragma unroll
    for (int it = 0; it < 4; ++it) {
        int r8 = (wave * 4 + it) * 8;
        gl16(Wob + (size_t)(m0 + r8 + srow) * 512 + scol, &Bs[0][r8][0]);
    }

    int cur = 0;
    for (int kt = 0; kt < 512; kt += 64) {
        if (kt + 64 < 512) {
#pragma unroll
            for (int it = 0; it < 2; ++it) {
                int r8 = (wave * 2 + it) * 8;
                gl16(X + (size_t)(n0 + r8 + srow) * 512 + kt + 64 + scol, &As[cur ^ 1][r8][0]);
            }
#pragma unroll
            for (int it = 0; it < 4; ++it) {
                int r8 = (wave * 4 + it) * 8;
                gl16(Wob + (size_t)(m0 + r8 + srow) * 512 + kt + 64 + scol, &Bs[cur ^ 1][r8][0]);
            }
            asm volatile("s_waitcnt vmcnt(6)" ::: "memory");
        } else {
            asm volatile("s_waitcnt vmcnt(0)" ::: "memory");
        }
        __builtin_amdgcn_s_barrier();
#pragma unroll
        for (int kk = 0; kk < 2; ++kk) {
            bf16x8 a[2], bb[4];
#pragma unroll
            for (int i = 0; i < 2; ++i)
                a[i] = *(const bf16x8*)&As[cur][wr + i * 16 + lrow][(kk * 32 + lkg * 8) ^ swr];
#pragma unroll
            for (int j = 0; j < 4; ++j)
                bb[j] = *(const bf16x8*)&Bs[cur][wc + j * 16 + lrow][(kk * 32 + lkg * 8) ^ swr];
#pragma unroll
            for (int i = 0; i < 2; ++i)
#pragma unroll
                for (int j = 0; j < 4; ++j)
                    acc[i][j] = mfma16(a[i], bb[j], acc[i][j]);
        }
        asm volatile("s_waitcnt lgkmcnt(0)" ::: "memory");
        __builtin_amdgcn_s_barrier();
        cur ^= 1;
    }
#pragma unroll
    for (int i = 0; i < 2; ++i) {
        int nbase = n0 + wr + i * 16 + lkg * 4;
#pragma unroll
        for (int j = 0; j < 4; ++j) {
            int m = m0 + wc + j * 16 + lrow;
            float bb = bo[m];
#pragma unroll
            for (int qq = 0; qq < 4; ++qq)
                fout[(size_t)(nbase + qq) * 512 + m] = acc[i][j][qq] + bb;
        }
    }
}

// ---------------------------------------------------------------------------
// bd_gemm v6: 128x128 tile, single stage, linear-F scatter, XOR-swizzled
// LDS reads.  F = 1025*u + p - 1023; mask bit index == F; diagonal by p0==0.
// ---------------------------------------------------------------------------
__global__ __launch_bounds__(256) void bd_gemm(
    const unsigned short* __restrict__ qv, const unsigned short* __restrict__ ph,
    const uint32_t* __restrict__ mbits, unsigned short* __restrict__ bds,
    int bh_base)
{
    int id = blockIdx.x, wg;
    if (gridDim.x == 4096) wg = (id & 7) * 512 + (id >> 3);
    else                   wg = (id & 7) * 64 + (id >> 3);
    const int zz = wg >> 6, rem = wg & 63;
    const int u0 = (rem & 7) * 128, p0 = (rem >> 3) * 128;
    const int bh = bh_base + zz;
    const int b = bh >> 3, h = bh & 7;
    __shared__ unsigned short As[128][64];
    __shared__ unsigned short Bs[128][64];
    const int tid = threadIdx.x, lane = tid & 63, wave = tid >> 6;
    const int lrow = lane & 15, lkg = lane >> 4;
    const int wr = (wave >> 1) * 64, wc = (wave & 1) * 64;
    const int srow = lane >> 3;
    const int scol = ((lane & 7) ^ (srow & 7)) * 8;   // swizzled source col
    const int swr  = (lrow & 7) * 8;                  // read-side XOR

#pragma unroll
    for (int it = 0; it < 4; ++it) {
        int r8 = (wave * 4 + it) * 8;
        gl16(qv + ((size_t)(b * 1024 + u0 + r8 + srow)) * 512 + h * 64 + scol, &As[r8][0]);
        gl16(ph + ((size_t)(p0 + r8 + srow)) * 512 + h * 64 + scol, &Bs[r8][0]);
    }
    __syncthreads();

    f32x4 acc[4][4];
#pragma unroll
    for (int i = 0; i < 4; ++i)
#pragma unroll
        for (int j = 0; j < 4; ++j) acc[i][j] = f32x4{0.f, 0.f, 0.f, 0.f};
#pragma unroll
    for (int kk = 0; kk < 2; ++kk) {
        bf16x8 a[4], bb[4];
#pragma unroll
        for (int i = 0; i < 4; ++i)
            a[i] = *(const bf16x8*)&As[wr + i * 16 + lrow][(kk * 32 + lkg * 8) ^ swr];
#pragma unroll
        for (int j = 0; j < 4; ++j)
            bb[j] = *(const bf16x8*)&Bs[wc + j * 16 + lrow][(kk * 32 + lkg * 8) ^ swr];
#pragma unroll
        for (int i = 0; i < 4; ++i)
#pragma unroll
            for (int j = 0; j < 4; ++j)
                acc[i][j] = mfma16(a[i], bb[j], acc[i][j]);
    }

    unsigned short* slab = bds + ((size_t)zz << 20);
    const uint32_t* mb = mbits + ((size_t)b << 15);   // this batch's 2^20-bit slab
    // F(i,j,qq) = 1025*u + p - 1023,  u = u0+wr+lkg*4 + i*16+qq,  p = p0+wc+lrow + j*16
    const int Cbase = 1025 * (u0 + wr + lkg * 4) + (p0 + wc + lrow) - 1023;
#pragma unroll
    for (int i = 0; i < 4; ++i) {
#pragma unroll
        for (int qq = 0; qq < 4; ++qq) {
            int Fb = Cbase + 1025 * (i * 16 + qq);
            int w0 = Fb >> 5;                          // may be negative (F<0 elems only)
            uint32_t mw0 = mb[w0], mw1 = mb[w0 + 1], mw2 = mb[w0 + 2];
            uint64_t m01 = ((uint64_t)mw1 << 32) | mw0;
            uint64_t m12 = ((uint64_t)mw2 << 32) | mw1;
            int sh = Fb & 31;
#pragma unroll
            for (int j = 0; j < 4; ++j) {
                uint32_t bit = (j < 2) ? ((uint32_t)(m01 >> (sh + j * 16)) & 1u)
                                       : ((uint32_t)(m12 >> (sh + (j - 2) * 16)) & 1u);
                unsigned short val = bit ? f2bf_native(acc[i][j][qq] * SC2)
                                         : (unsigned short)NEGBF;
                int F = Fb + j * 16;
                if (F >= 0) slab[F] = val;
            }
        }
    }

    // diagonal t'=u'+1 (never produced by the linear map)
    if (p0 == 0 && tid < 128) {
        int ud = u0 + tid;
        if (ud < 1023) {
            const uint8_t* mrowbytes = (const uint8_t*)mbits + ((size_t)b << 17);
            uint32_t bit = (mrowbytes[ud * 128 + ((ud + 1) >> 3)] >> ((ud + 1) & 7)) & 1;
            slab[((size_t)ud << 10) + (ud + 1)] = bit ? 0 : (unsigned short)NEGBF;
        }
    }
}

// ---------------------------------------------------------------------------
// attn12: flash attention, KVBLK=64, static-max exp2 softmax, dbuf K/V via
// gl16 with counted vmcnt(4) raw-barrier pipeline, XOR-swizzled LDS, and
// s_setprio(1) around the MFMA clusters.
// ---------------------------------------------------------------------------
__global__ __launch_bounds__(256, 4) void attn12(
    const unsigned short* __restrict__ qu, const unsigned short* __restrict__ kh,
    const unsigned short* __restrict__ vT, const unsigned short* __restrict__ bds,
    unsigned short* __restrict__ xout, int b_base)
{
    int id = blockIdx.x, nid, b, rem;
    if (gridDim.x == 1024) {
        nid = (id & 7) * 128 + (id >> 3);
        b = b_base + (nid >> 7); rem = nid & 127;
    } else {
        nid = (id & 7) * 16 + (id >> 3);
        b = b_base; rem = nid;
    }
    const int h = rem >> 4, ublk = rem & 15;
    const int u0 = ublk * 64;

    __shared__ unsigned short Ks[2][64][64];
    __shared__ unsigned short Vs[2][64][64];
    __shared__ unsigned short Ps[4][16][64];
    const int tid = threadIdx.x, lane = tid & 63, wave = tid >> 6;
    const int lrow = lane & 15, lkg = lane >> 4;
    const int srow = lane >> 3;
    const int scol = ((lane & 7) ^ (srow & 7)) * 8;   // swizzled source col
    const int swr  = (lrow & 7) * 8;                  // read-side XOR
    const f32x4 zero = {0.f, 0.f, 0.f, 0.f};

    const unsigned short* qub = qu + ((size_t)(b * 1024 + u0 + wave * 16 + lrow)) * 512 + h * 64;
    bf16x8 au0 = *(const bf16x8*)(qub + lkg * 8);
    bf16x8 au1 = *(const bf16x8*)(qub + 32 + lkg * 8);

    const int urow = u0 + wave * 16 + lkg * 4;           // +q
    const int zoff = (b - b_base) * 8 + h;
    const unsigned short* bdp[4];
#pragma unroll
    for (int q = 0; q < 4; ++q)
        bdp[q] = bds + ((size_t)zoff << 20) + (((size_t)(urow + q)) << 10) + lrow;
    const unsigned short* kbase = kh + ((size_t)(b * 1024)) * 512 + h * 64;
    const unsigned short* vbase = vT + (((size_t)((b * 8 + h) * 64)) << 10);

    f32x4 acc[4] = {zero, zero, zero, zero};
    float lsum[4] = {0.f, 0.f, 0.f, 0.f};

    // prologue: stage tile 0
#pragma unroll
    for (int it = 0; it < 2; ++it) {
        int r8 = (wave * 2 + it) * 8;
        gl16(kbase + (size_t)(r8 + srow) * 512 + scol, &Ks[0][r8][0]);
        gl16(vbase + ((size_t)(r8 + srow) << 10) + scol, &Vs[0][r8][0]);
    }

    int cur = 0;
    for (int t0 = 0; t0 < 1024; t0 += 64) {
        // BD reg loads first (compiler tracks their reg deps itself)
        f32x4 bdC[4];
#pragma unroll
        for (int j = 0; j < 4; ++j)
#pragma unroll
            for (int q = 0; q < 4; ++q)
                bdC[j][q] = __uint_as_float(((uint32_t)bdp[q][j * 16]) << 16);
#pragma unroll
        for (int q = 0; q < 4; ++q) bdp[q] += 64;

        if (t0 < 960) {   // prefetch next K/V tile into other buffer
#pragma unroll
            for (int it = 0; it < 2; ++it) {
                int r8 = (wave * 2 + it) * 8;
                gl16(kbase + (size_t)(t0 + 64 + r8 + srow) * 512 + scol, &Ks[cur ^ 1][r8][0]);
                gl16(vbase + ((size_t)(r8 + srow) << 10) + t0 + 64 + scol, &Vs[cur ^ 1][r8][0]);
            }
            asm volatile("s_waitcnt vmcnt(4)" ::: "memory");  // BD + prev prefetch landed
        } else {
            asm volatile("s_waitcnt vmcnt(0)" ::: "memory");
        }
        __builtin_amdgcn_s_barrier();   // tile-t0 K/V visible to all waves

        f32x4 s[4];
        __builtin_amdgcn_s_setprio(1);
#pragma unroll
        for (int j = 0; j < 4; ++j) {
            bf16x8 k0 = *(const bf16x8*)&Ks[cur][j * 16 + lrow][(lkg * 8) ^ swr];
            bf16x8 k1 = *(const bf16x8*)&Ks[cur][j * 16 + lrow][(32 + lkg * 8) ^ swr];
            s[j] = mfma16(au1, k1, mfma16(au0, k0, bdC[j]));
        }
        __builtin_amdgcn_s_setprio(0);
        // static-max softmax: P = exp2(s) directly
#pragma unroll
        for (int j = 0; j < 4; ++j) {
#pragma unroll
            for (int q = 0; q < 4; ++q) {
                float p = exp2f(s[j][q]);
                lsum[q] += p;
                int prow = lkg * 4 + q;
                Ps[wave][prow][(j * 16 + lrow) ^ ((prow & 7) * 8)] = f2bf_native(p);
            }
        }
        bf16x8 pa0 = *(const bf16x8*)&Ps[wave][lrow][(lkg * 8) ^ swr];
        bf16x8 pa1 = *(const bf16x8*)&Ps[wave][lrow][(32 + lkg * 8) ^ swr];
        __builtin_amdgcn_s_setprio(1);
#pragma unroll
        for (int jj = 0; jj < 4; ++jj) {
            bf16x8 vb0 = *(const bf16x8*)&Vs[cur][jj * 16 + lrow][(lkg * 8) ^ swr];
            bf16x8 vb1 = *(const bf16x8*)&Vs[cur][jj * 16 + lrow][(32 + lkg * 8) ^ swr];
            acc[jj] = mfma16(pa1, vb1, mfma16(pa0, vb0, acc[jj]));
        }
        __builtin_amdgcn_s_setprio(0);
        asm volatile("s_waitcnt lgkmcnt(0)" ::: "memory");  // my reads of cur done
        __builtin_amdgcn_s_barrier();   // safe for next prefetch to overwrite cur^1
        cur ^= 1;
    }

#pragma unroll
    for (int off = 1; off < 16; off <<= 1)
#pragma unroll
        for (int q = 0; q < 4; ++q) lsum[q] += __shfl_xor(lsum[q], off);
#pragma unroll
    for (int q = 0; q < 4; ++q) {
        float inv = 1.0f / lsum[q];
        int u = urow + q;
#pragma unroll
        for (int jj = 0; jj < 4; ++jj) {
            int d = jj * 16 + lrow;
            xout[((size_t)(b * 1024 + u)) * 512 + h * 64 + d] = f2bf_native(acc[jj][q] * inv);
        }
    }
}

// ---------------------------------------------------------------------------
extern "C" void kernel_launch(void* const* d_in, const int* in_sizes, int n_in,
                              void* d_out, int out_size, void* d_ws, size_t ws_size,
                              hipStream_t stream) {
    const float* q    = (const float*)d_in[0];
    const float* k    = (const float*)d_in[1];
    const float* v    = (const float*)d_in[2];
    const float* pos  = (const float*)d_in[3];
    const int*   mask = (const int*)d_in[4];
    const float* Wq   = (const float*)d_in[5];
    const float* bq   = (const float*)d_in[6];
    const float* Wk   = (const float*)d_in[7];
    const float* bk   = (const float*)d_in[8];
    const float* Wv   = (const float*)d_in[9];
    const float* bv   = (const float*)d_in[10];
    const float* Wo   = (const float*)d_in[11];
    const float* bo   = (const float*)d_in[12];
    const float* Wp   = (const float*)d_in[13];
    const float* bias_u = (const float*)d_in[14];
    const float* bias_v = (const float*)d_in[15];
    float* out = (float*)d_out;

    unsigned short* ws = (unsigned short*)d_ws;
    constexpr size_t NQ  = (size_t)Bc * Tc * Dc;          // 4,194,304 elems
    constexpr size_t NP  = (size_t)Tc * Dc;               // 524,288
    constexpr size_t NMB = (size_t)Bc * Tc * 32;          // 262,144 words
    constexpr size_t NWB = (size_t)5 * 262144;            // 1,310,720 elems
    unsigned short* ws_qu = ws;
    unsigned short* ws_qv = ws_qu + NQ;
    unsigned short* ws_kh = ws_qv + NQ;
    unsigned short* ws_vT = ws_kh + NQ;
    unsigned short* ws_ph = ws_vT + NQ;
    uint32_t*       ws_mb = (uint32_t*)(ws_ph + NP);
    unsigned short* ws_wb = (unsigned short*)(ws_mb + NMB);
    unsigned short* ws_qb = ws_wb + NWB;      // conversion area (dead after proj4)
    unsigned short* ws_kb = ws_qb + NQ;
    unsigned short* ws_vb = ws_kb + NQ;
    unsigned short* ws_pb = ws_vb + NQ;
    unsigned short* ws_bd = ws_qb;            // BD overlays the conversion area

    constexpr size_t BD_FULL  = (size_t)64 * 1024 * 1024;   // elems
    constexpr size_t BD_SMALL = (size_t)8 * 1024 * 1024;
    const size_t base_bytes = (4 * NQ + NP + NWB) * 2 + NMB * 4;
    const bool full  = ws_size >= base_bytes + BD_FULL * 2;
    const bool tier2 = !full && ws_size >= base_bytes + ((3 * NQ + NP) + NQ) * 2;

    dim3 blk(256);
    prep<<<39808, blk, 0, stream>>>(mask, ws_mb, Wq, Wk, Wv, Wp, Wo, ws_wb,
                                    q, k, v, pos, ws_qb, ws_kb, ws_vb, ws_pb);
    proj4<<<1600, blk, 0, stream>>>(ws_qb, ws_kb, ws_vb, ws_pb, ws_wb, bq, bk, bv,
                                    bias_u, bias_v, ws_qu, ws_qv, ws_kh, ws_vT, ws_ph);

    if (full) {
        unsigned short* ws_x = ws_qv;  // qv dead after bd_gemm
        bd_gemm<<<4096, blk, 0, stream>>>(ws_qv, ws_ph, ws_mb, ws_bd, 0);
        attn12<<<1024, blk, 0, stream>>>(ws_qu, ws_kh, ws_vT, ws_bd, ws_x, 0);
        gemm_out<<<512, blk, 0, stream>>>(ws_x, ws_wb + 4 * 262144, bo, out);
    } else if (tier2) {
        unsigned short* ws_x = ws_qb + 3 * NQ + NP;
        for (int b = 0; b < 8; ++b) {
            bd_gemm<<<512, blk, 0, stream>>>(ws_qv, ws_ph, ws_mb, ws_bd, b * 8);
            attn12<<<128, blk, 0, stream>>>(ws_qu, ws_kh, ws_vT, ws_bd, ws_x, b);
        }
        gemm_out<<<512, blk, 0, stream>>>(ws_x, ws_wb + 4 * 262144, bo, out);
    }
}